// Round 2
// baseline (449.751 us; speedup 1.0000x reference)
//
#include <hip/hip_runtime.h>
#include <hip/hip_bf16.h>

// BiPairwiseNegativeCELoss on MI355X.
// Inputs: q, d, nd : [16384, 128] fp32. Output: scalar fp32 loss.
// loss = 0.5 * ( mean(softplus(q.nd_row - q.d_row))
//              + mean(softplus(max_c(q_b . d_c, diag -1e6) - q_b.d_b)) )
//
// R10: occupancy, not scheduling. R8 (dbuf+syncthreads) and R9 (4-buf ring,
// counted vmcnt, raw barriers, cross-chunk pre-read) BOTH land at ~59 us /
// MfmaUtil 46% -- intra-wave reordering is not the constraint. Correct
// per-SIMD accounting: 16x16x32 bf16 MFMA ~19.4 cyc/SIMD; per chunk per SIMD
// = 2 waves x 64 MFMA = ~2480 cyc vs wall ~4490. No pipe saturated (matrix
// 55%, LDS ~34%, VALU 28%) => latency-bound at 2 waves/SIMD. Fix: 2x16KB LDS
// (32 KB/block) + __launch_bounds__(256,4) -> 4 blocks/CU = 4 waves/SIMD,
// and the whole 1024-block grid is resident in ONE round (256 CU x 4).
// Independent blocks' barriers don't align, so each block's drain/LDS burst
// hides under the other blocks' MFMA (m114 implicit overlap). Keep intra-
// chunk B-fragment register pipelining, hoisted zinit, setprio around MFMA.
// Same shapes/layouts/numerics as R8/R9 (absmax must stay 0.0).

#define BATCH 16384
#define DDIM  128
#define NWAVES 4                 // 256 threads
#define ROWS_PER_BLOCK 256       // 4 waves x 64 rows
#define COLS_PER_BLOCK 1024      // 16 col-groups
#define CHUNK_COLS 64            // 16 KB bf16 per chunk buffer
#define NCHUNKS (COLS_PER_BLOCK / CHUNK_COLS)   // 16
#define CHUNK_USHORTS (CHUNK_COLS * DDIM)       // 8192
#define NCG (BATCH / COLS_PER_BLOCK)            // 16
#define NRG (BATCH / ROWS_PER_BLOCK)            // 64
#define NPREP 2048                               // prep blocks (8 rows each)
#define NRED  64                                 // reduce blocks

typedef __attribute__((ext_vector_type(8))) short bf16x8;   // 8 bf16 = 4 VGPRs
typedef __attribute__((ext_vector_type(4))) float f32x4;

__device__ __forceinline__ float softplus_f(float x) {
    return (x > 0.0f) ? x + log1pf(expf(-x)) : log1pf(expf(x));
}

__device__ __forceinline__ ushort f2bf_rne(float x) {
    unsigned u = __float_as_uint(x);
    unsigned r = (u + 0x7FFFu + ((u >> 16) & 1u)) >> 16;
    return (ushort)r;
}

#define WAITVM(n) do { \
        __builtin_amdgcn_s_waitcnt((n) | (7 << 4) | (15 << 8)); \
        asm volatile("" ::: "memory"); \
    } while (0)

#define BARRIER() do { \
        __builtin_amdgcn_s_barrier(); \
        asm volatile("" ::: "memory"); \
    } while (0)

// ---------------------------------------------------------------------------
// Kernel A: pairwise dots (fp32 exact), loss1 block partials, bf16 casts.
// 2048 blocks x 256 threads. Block owns 8 rows; 32 threads per row.
// ---------------------------------------------------------------------------
__global__ __launch_bounds__(256) void prep_kernel(
    const float* __restrict__ q, const float* __restrict__ d,
    const float* __restrict__ nd,
    ushort* __restrict__ qb, ushort* __restrict__ db,
    float* __restrict__ pos, float* __restrict__ loss1_part)
{
    const int t   = threadIdx.x;
    const int sub = t >> 5;                      // row 0..7 within block
    const int ln  = t & 31;                      // 32 threads per row
    const int row = blockIdx.x * 8 + sub;
    const size_t idx = (size_t)row * DDIM + ln * 4;

    float4 a = *(const float4*)(q  + idx);
    float4 b = *(const float4*)(d  + idx);
    float4 c = *(const float4*)(nd + idx);

    ushort4 o;
    o.x = f2bf_rne(a.x); o.y = f2bf_rne(a.y);
    o.z = f2bf_rne(a.z); o.w = f2bf_rne(a.w);
    *(ushort4*)(qb + idx) = o;
    ushort4 p;
    p.x = f2bf_rne(b.x); p.y = f2bf_rne(b.y);
    p.z = f2bf_rne(b.z); p.w = f2bf_rne(b.w);
    *(ushort4*)(db + idx) = p;

    float ps = a.x * b.x + a.y * b.y + a.z * b.z + a.w * b.w;
    float ns = a.x * c.x + a.y * c.y + a.z * c.z + a.w * c.w;
    ps += __shfl_xor(ps, 1); ps += __shfl_xor(ps, 2);
    ps += __shfl_xor(ps, 4); ps += __shfl_xor(ps, 8);
    ps += __shfl_xor(ps, 16);
    ns += __shfl_xor(ns, 1); ns += __shfl_xor(ns, 2);
    ns += __shfl_xor(ns, 4); ns += __shfl_xor(ns, 8);
    ns += __shfl_xor(ns, 16);

    float contrib = 0.0f;
    if (ln == 0) {
        pos[row] = ps;                     // == scores[b][b], exact fp32
        contrib = softplus_f(ns - ps);
    }
    contrib += __shfl_xor(contrib, 32);    // combine the wave's two rows

    __shared__ float red[4];
    if ((t & 63) == 0) red[t >> 6] = contrib;
    __syncthreads();
    if (t == 0)
        loss1_part[blockIdx.x] = red[0] + red[1] + red[2] + red[3];
}

// ---------------------------------------------------------------------------
// Kernel B: fused GEMM + row-max. 1024 blocks x 256 threads, 4 blocks/CU
// (whole grid resident in one round). Block (rg = bx&63, cg = bx>>6):
// rows [rg*256, +256), cols [cg*1024, +1024). Wave w owns 64 rows (A in
// registers, whole K). B staged cooperatively: 64-col chunks, 2x16KB LDS
// double buffer, XOR-swizzled 16B k-segments. Intra-chunk B-fragment
// register pipelining; 4 waves/SIMD provide the latency hiding that R8/R9's
// 2 waves/SIMD lacked.
// ---------------------------------------------------------------------------
__global__ __launch_bounds__(256, 4) void inbatch_kernel(
    const ushort* __restrict__ qb, const ushort* __restrict__ db,
    float* __restrict__ partials)
{
    __shared__ ushort stg[2][CHUNK_USHORTS];   // 2 x 16 KB

    const int t      = threadIdx.x;
    const int w      = t >> 6;
    const int l      = t & 63;
    const int lane16 = l & 15;
    const int quad   = l >> 4;
    const int rg     = blockIdx.x & 63;
    const int cg     = blockIdx.x >> 6;
    const int rows0  = rg * ROWS_PER_BLOCK + w * 64;   // this wave's 64 rows
    const int col0   = cg * COLS_PER_BLOCK;

    // A fragments: lane l holds Q[rows0 + rs*16 + (l&15)][ks*32 + quad*8 + j]
    bf16x8 afrag[4][4];
#pragma unroll
    for (int rs = 0; rs < 4; ++rs)
#pragma unroll
        for (int ks = 0; ks < 4; ++ks)
            afrag[rs][ks] = *(const bf16x8*)(
                qb + (size_t)(rows0 + rs * 16 + lane16) * DDIM + ks * 32 + quad * 8);

    // staging: thread t handles 16B segments i*256 + t (i = 0..3) per chunk;
    // col = i*16 + (t>>4), LDS slot = t&15, global kseg = (t&15)^((t>>4)&15)
    const ushort* gsrc[4];
#pragma unroll
    for (int i = 0; i < 4; ++i) {
        int c = i * 16 + (t >> 4);
        gsrc[i] = db + (size_t)(col0 + c) * DDIM + (((t & 15) ^ ((t >> 4) & 15)) * 8);
    }

    // ds_read base (ushort offsets); per-(ct,buf) selected by pointer + imm
    int dsbase[4];
#pragma unroll
    for (int ks = 0; ks < 4; ++ks)
        dsbase[ks] = lane16 * DDIM + (((ks * 4 + quad) ^ lane16) * 8);

    const f32x4 zinit = {0.0f, 0.0f, 0.0f, 0.0f};   // hoisted acc init

    float runmax[4][4];
#pragma unroll
    for (int rs = 0; rs < 4; ++rs)
#pragma unroll
        for (int r = 0; r < 4; ++r) runmax[rs][r] = -3.0e38f;

    // prologue: stage chunk 0 into buf 0 (LDS dest wave-uniform + lane*16B)
#pragma unroll
    for (int i = 0; i < 4; ++i)
        __builtin_amdgcn_global_load_lds(
            (const __attribute__((address_space(1))) void*)gsrc[i],
            (__attribute__((address_space(3))) void*)(&stg[0][0] + (i * 256 + w * 64) * 8),
            16, 0, 0);

    for (int ch = 0; ch < NCHUNKS; ++ch) {
        // outstanding at this wait: exactly chunk ch's 4 loads (issued last
        // iteration, had the whole previous compute phase to land)
        WAITVM(0);
        BARRIER();                           // chunk ch visible; buf ch^1 free
        if (ch + 1 < NCHUNKS) {              // prefetch next chunk now; it has
#pragma unroll                               // the whole compute phase to land
            for (int i = 0; i < 4; ++i)
                __builtin_amdgcn_global_load_lds(
                    (const __attribute__((address_space(1))) void*)(gsrc[i] + (size_t)(ch + 1) * CHUNK_USHORTS),
                    (__attribute__((address_space(3))) void*)(&stg[(ch + 1) & 1][0] + (i * 256 + w * 64) * 8),
                    16, 0, 0);
        }

        const ushort* buf = &stg[ch & 1][0];

        // software pipeline: bcur = tile ct, bnxt = tile ct+1 (in flight
        // under tile ct's MFMA burst)
        bf16x8 bcur[4];
#pragma unroll
        for (int ks = 0; ks < 4; ++ks)
            bcur[ks] = *(const bf16x8*)(buf + dsbase[ks]);

#pragma unroll
        for (int ct = 0; ct < 4; ++ct) {
            bf16x8 bnxt[4];
            if (ct < 3) {
#pragma unroll
                for (int ks = 0; ks < 4; ++ks)
                    bnxt[ks] = *(const bf16x8*)(buf + dsbase[ks] + (ct + 1) * 2048);
            }

            const int ctile = col0 + ch * CHUNK_COLS + ct * 16;
            __builtin_amdgcn_s_setprio(1);
#pragma unroll
            for (int rs = 0; rs < 4; ++rs) {
                f32x4 s = __builtin_amdgcn_mfma_f32_16x16x32_bf16(
                    afrag[rs][0], bcur[0], zinit, 0, 0, 0);
#pragma unroll
                for (int ks = 1; ks < 4; ++ks)
                    s = __builtin_amdgcn_mfma_f32_16x16x32_bf16(
                        afrag[rs][ks], bcur[ks], s, 0, 0, 0);
                if (ctile == rows0 + rs * 16) {    // diagonal tile: -1e6
#pragma unroll
                    for (int r = 0; r < 4; ++r)
                        if (quad * 4 + r == lane16) s[r] -= 1.0e6f;
                }
#pragma unroll
                for (int r = 0; r < 4; ++r)
                    runmax[rs][r] = fmaxf(runmax[rs][r], s[r]);
            }
            __builtin_amdgcn_s_setprio(0);

            if (ct < 3) {
#pragma unroll
                for (int ks = 0; ks < 4; ++ks) bcur[ks] = bnxt[ks];
            }
        }
    }

    // reduce max across the 16 lanes (cols) of each quad-group
#pragma unroll
    for (int rs = 0; rs < 4; ++rs)
#pragma unroll
        for (int r = 0; r < 4; ++r) {
            float m = runmax[rs][r];
            m = fmaxf(m, __shfl_xor(m, 1));
            m = fmaxf(m, __shfl_xor(m, 2));
            m = fmaxf(m, __shfl_xor(m, 4));
            m = fmaxf(m, __shfl_xor(m, 8));
            runmax[rs][r] = m;
        }

    // partial row-max for this col-group -> global [NCG][BATCH]
    if (lane16 == 0) {
#pragma unroll
        for (int rs = 0; rs < 4; ++rs)
#pragma unroll
            for (int r = 0; r < 4; ++r)
                partials[(size_t)cg * BATCH + rows0 + rs * 16 + quad * 4 + r] =
                    runmax[rs][r];
    }
}

// ---------------------------------------------------------------------------
// Kernel C: combine col-group partials, softplus, per-block sums (no atomics).
// ---------------------------------------------------------------------------
__global__ __launch_bounds__(256) void reduce_kernel(
    const float* __restrict__ partials, const float* __restrict__ pos,
    float* __restrict__ red_part)
{
    const int t = threadIdx.x;
    const int r = blockIdx.x * 256 + t;
    float fm = partials[r];
#pragma unroll
    for (int cgi = 1; cgi < NCG; ++cgi)
        fm = fmaxf(fm, partials[(size_t)cgi * BATCH + r]);
    float c = softplus_f(fm - pos[r]);
    c += __shfl_xor(c, 1);  c += __shfl_xor(c, 2);
    c += __shfl_xor(c, 4);  c += __shfl_xor(c, 8);
    c += __shfl_xor(c, 16); c += __shfl_xor(c, 32);

    __shared__ float red[4];
    if ((t & 63) == 0) red[t >> 6] = c;
    __syncthreads();
    if (t == 0)
        red_part[blockIdx.x] = red[0] + red[1] + red[2] + red[3];
}

// ---------------------------------------------------------------------------
// Kernel D: final sum of loss1_part[2048] + red_part[64] -> scalar loss.
// ---------------------------------------------------------------------------
__global__ __launch_bounds__(256) void finalize_kernel(
    const float* __restrict__ loss1_part, const float* __restrict__ red_part,
    float* __restrict__ out)
{
    const int t = threadIdx.x;
    float s = 0.0f;
#pragma unroll
    for (int i = 0; i < NPREP / 256; ++i)
        s += loss1_part[i * 256 + t];
    if (t < NRED) s += red_part[t];
    s += __shfl_xor(s, 1);  s += __shfl_xor(s, 2);
    s += __shfl_xor(s, 4);  s += __shfl_xor(s, 8);
    s += __shfl_xor(s, 16); s += __shfl_xor(s, 32);

    __shared__ float red[4];
    if ((t & 63) == 0) red[t >> 6] = s;
    __syncthreads();
    if (t == 0)
        out[0] = (red[0] + red[1] + red[2] + red[3]) * (1.0f / (2.0f * BATCH));
}

extern "C" void kernel_launch(void* const* d_in, const int* in_sizes, int n_in,
                              void* d_out, int out_size, void* d_ws, size_t ws_size,
                              hipStream_t stream)
{
    const float* q  = (const float*)d_in[0];
    const float* d  = (const float*)d_in[1];
    const float* nd = (const float*)d_in[2];
    float* out = (float*)d_out;

    char* ws = (char*)d_ws;
    float*  pos        = (float*)ws;                                 // 64 KB
    ushort* qb         = (ushort*)(ws + 65536);                      // 4 MB
    ushort* db         = (ushort*)(ws + 65536 + 4194304);            // 4 MB
    float*  partials   = (float*)(ws + 65536 + 2 * 4194304);         // 1 MB
    float*  loss1_part = (float*)(ws + 65536 + 2 * 4194304 + 1048576);     // 8 KB
    float*  red_part   = (float*)(ws + 65536 + 2 * 4194304 + 1048576 + 8192); // 256 B

    prep_kernel<<<NPREP, 256, 0, stream>>>(q, d, nd, qb, db, pos, loss1_part);
    inbatch_kernel<<<NRG * NCG, 256, 0, stream>>>(qb, db, partials);
    reduce_kernel<<<NRED, 256, 0, stream>>>(partials, pos, red_part);
    finalize_kernel<<<1, 256, 0, stream>>>(loss1_part, red_part, out);
}

// Round 3
// 404.684 us; speedup vs baseline: 1.1114x; 1.1114x over previous
//
#include <hip/hip_runtime.h>
#include <hip/hip_bf16.h>

// BiPairwiseNegativeCELoss on MI355X.
// Inputs: q, d, nd : [16384, 128] fp32. Output: scalar fp32 loss.
// loss = 0.5 * ( mean(softplus(q.nd_row - q.d_row))
//              + mean(softplus(max_c(q_b . d_c, diag -1e6) - q_b.d_b)) )
//
// R11: occupancy WITH a register budget that fits. R10's (256,4) forced
// VGPR_Count=64 and spilled afrag to scratch (FETCH_SIZE 18.5MB -> 1.18GB,
// 386us). R8/R9's 2-blocks/CU (combined VGPR+AGPR ~160 -> 256-reg granule)
// is why scheduling tweaks were null: 2 waves/SIMD can't hide latency.
// Fix: trim register demand to ~122 combined so (256,4) fits WITHOUT spill:
//   - drop the bnxt register double-buffer (-16 regs). At 4 waves/SIMD, TLP
//     does the hiding: per tile a wave stalls ~170cyc on 4 ds_read_b128 then
//     bursts 16 MFMA (~310cyc); 4 waves oversubscribe the matrix pipe 2.6x.
//   - 4 blocks/CU => whole 1024-block grid resident in ONE round.
// Throughput check: per SIMD MFMA = 4x1024x19.4 ~ 79.5k cyc ~ 33us;
// LDS ~3.6k cyc per 4 block-chunks < MFMA 4.9k => compute-limited.
// Watch: if FETCH_SIZE explodes again, the allocator spilled -> revert.
// Same shapes/layouts/numerics as R8 (absmax must stay 0.0).

#define BATCH 16384
#define DDIM  128
#define NWAVES 4                 // 256 threads
#define ROWS_PER_BLOCK 256       // 4 waves x 64 rows
#define COLS_PER_BLOCK 1024      // 16 col-groups
#define CHUNK_COLS 64            // 16 KB bf16 per chunk buffer
#define NCHUNKS (COLS_PER_BLOCK / CHUNK_COLS)   // 16
#define CHUNK_USHORTS (CHUNK_COLS * DDIM)       // 8192
#define NCG (BATCH / COLS_PER_BLOCK)            // 16
#define NRG (BATCH / ROWS_PER_BLOCK)            // 64
#define NPREP 2048                               // prep blocks (8 rows each)
#define NRED  64                                 // reduce blocks

typedef __attribute__((ext_vector_type(8))) short bf16x8;   // 8 bf16 = 4 VGPRs
typedef __attribute__((ext_vector_type(4))) float f32x4;

__device__ __forceinline__ float softplus_f(float x) {
    return (x > 0.0f) ? x + log1pf(expf(-x)) : log1pf(expf(x));
}

__device__ __forceinline__ ushort f2bf_rne(float x) {
    unsigned u = __float_as_uint(x);
    unsigned r = (u + 0x7FFFu + ((u >> 16) & 1u)) >> 16;
    return (ushort)r;
}

#define WAITVM(n) do { \
        __builtin_amdgcn_s_waitcnt((n) | (7 << 4) | (15 << 8)); \
        asm volatile("" ::: "memory"); \
    } while (0)

#define BARRIER() do { \
        __builtin_amdgcn_s_barrier(); \
        asm volatile("" ::: "memory"); \
    } while (0)

// ---------------------------------------------------------------------------
// Kernel A: pairwise dots (fp32 exact), loss1 block partials, bf16 casts.
// 2048 blocks x 256 threads. Block owns 8 rows; 32 threads per row.
// ---------------------------------------------------------------------------
__global__ __launch_bounds__(256) void prep_kernel(
    const float* __restrict__ q, const float* __restrict__ d,
    const float* __restrict__ nd,
    ushort* __restrict__ qb, ushort* __restrict__ db,
    float* __restrict__ pos, float* __restrict__ loss1_part)
{
    const int t   = threadIdx.x;
    const int sub = t >> 5;                      // row 0..7 within block
    const int ln  = t & 31;                      // 32 threads per row
    const int row = blockIdx.x * 8 + sub;
    const size_t idx = (size_t)row * DDIM + ln * 4;

    float4 a = *(const float4*)(q  + idx);
    float4 b = *(const float4*)(d  + idx);
    float4 c = *(const float4*)(nd + idx);

    ushort4 o;
    o.x = f2bf_rne(a.x); o.y = f2bf_rne(a.y);
    o.z = f2bf_rne(a.z); o.w = f2bf_rne(a.w);
    *(ushort4*)(qb + idx) = o;
    ushort4 p;
    p.x = f2bf_rne(b.x); p.y = f2bf_rne(b.y);
    p.z = f2bf_rne(b.z); p.w = f2bf_rne(b.w);
    *(ushort4*)(db + idx) = p;

    float ps = a.x * b.x + a.y * b.y + a.z * b.z + a.w * b.w;
    float ns = a.x * c.x + a.y * c.y + a.z * c.z + a.w * c.w;
    ps += __shfl_xor(ps, 1); ps += __shfl_xor(ps, 2);
    ps += __shfl_xor(ps, 4); ps += __shfl_xor(ps, 8);
    ps += __shfl_xor(ps, 16);
    ns += __shfl_xor(ns, 1); ns += __shfl_xor(ns, 2);
    ns += __shfl_xor(ns, 4); ns += __shfl_xor(ns, 8);
    ns += __shfl_xor(ns, 16);

    float contrib = 0.0f;
    if (ln == 0) {
        pos[row] = ps;                     // == scores[b][b], exact fp32
        contrib = softplus_f(ns - ps);
    }
    contrib += __shfl_xor(contrib, 32);    // combine the wave's two rows

    __shared__ float red[4];
    if ((t & 63) == 0) red[t >> 6] = contrib;
    __syncthreads();
    if (t == 0)
        loss1_part[blockIdx.x] = red[0] + red[1] + red[2] + red[3];
}

// ---------------------------------------------------------------------------
// Kernel B: fused GEMM + row-max. 1024 blocks x 256 threads, 4 blocks/CU
// (whole grid resident in one round). Block (rg = bx&63, cg = bx>>6):
// rows [rg*256, +256), cols [cg*1024, +1024). Wave w owns 64 rows (A in
// registers, whole K). B staged cooperatively: 64-col chunks, 2x16KB LDS
// double buffer, XOR-swizzled 16B k-segments. No intra-wave B pipeline --
// 4 waves/SIMD (independent blocks, unaligned phases) hide ds_read latency
// under each other's MFMA bursts. Register demand ~122 combined (afrag 64,
// bcur 16, runmax 16, addressing ~26) fits the 128-reg granule.
// ---------------------------------------------------------------------------
__global__ __launch_bounds__(256, 4) void inbatch_kernel(
    const ushort* __restrict__ qb, const ushort* __restrict__ db,
    float* __restrict__ partials)
{
    __shared__ ushort stg[2][CHUNK_USHORTS];   // 2 x 16 KB

    const int t      = threadIdx.x;
    const int w      = t >> 6;
    const int l      = t & 63;
    const int lane16 = l & 15;
    const int quad   = l >> 4;
    const int rg     = blockIdx.x & 63;
    const int cg     = blockIdx.x >> 6;
    const int rows0  = rg * ROWS_PER_BLOCK + w * 64;   // this wave's 64 rows
    const int col0   = cg * COLS_PER_BLOCK;

    // A fragments: lane l holds Q[rows0 + rs*16 + (l&15)][ks*32 + quad*8 + j]
    bf16x8 afrag[4][4];
#pragma unroll
    for (int rs = 0; rs < 4; ++rs)
#pragma unroll
        for (int ks = 0; ks < 4; ++ks)
            afrag[rs][ks] = *(const bf16x8*)(
                qb + (size_t)(rows0 + rs * 16 + lane16) * DDIM + ks * 32 + quad * 8);

    // staging: thread t handles 16B segments i*256 + t (i = 0..3) per chunk;
    // col = i*16 + (t>>4), LDS slot = t&15, global kseg = (t&15)^((t>>4)&15)
    const ushort* gsrc[4];
#pragma unroll
    for (int i = 0; i < 4; ++i) {
        int c = i * 16 + (t >> 4);
        gsrc[i] = db + (size_t)(col0 + c) * DDIM + (((t & 15) ^ ((t >> 4) & 15)) * 8);
    }

    // ds_read base (ushort offsets); per-(ct,buf) selected by pointer + imm
    int dsbase[4];
#pragma unroll
    for (int ks = 0; ks < 4; ++ks)
        dsbase[ks] = lane16 * DDIM + (((ks * 4 + quad) ^ lane16) * 8);

    const f32x4 zinit = {0.0f, 0.0f, 0.0f, 0.0f};   // hoisted acc init

    float runmax[4][4];
#pragma unroll
    for (int rs = 0; rs < 4; ++rs)
#pragma unroll
        for (int r = 0; r < 4; ++r) runmax[rs][r] = -3.0e38f;

    // prologue: stage chunk 0 into buf 0 (LDS dest wave-uniform + lane*16B)
#pragma unroll
    for (int i = 0; i < 4; ++i)
        __builtin_amdgcn_global_load_lds(
            (const __attribute__((address_space(1))) void*)gsrc[i],
            (__attribute__((address_space(3))) void*)(&stg[0][0] + (i * 256 + w * 64) * 8),
            16, 0, 0);

    for (int ch = 0; ch < NCHUNKS; ++ch) {
        // outstanding at this wait: exactly chunk ch's 4 loads (issued last
        // iteration, had the whole previous compute phase to land)
        WAITVM(0);
        BARRIER();                           // chunk ch visible; buf ch^1 free
        if (ch + 1 < NCHUNKS) {              // prefetch next chunk now; it has
#pragma unroll                               // the whole compute phase to land
            for (int i = 0; i < 4; ++i)
                __builtin_amdgcn_global_load_lds(
                    (const __attribute__((address_space(1))) void*)(gsrc[i] + (size_t)(ch + 1) * CHUNK_USHORTS),
                    (__attribute__((address_space(3))) void*)(&stg[(ch + 1) & 1][0] + (i * 256 + w * 64) * 8),
                    16, 0, 0);
        }

        const ushort* buf = &stg[ch & 1][0];

#pragma unroll
        for (int ct = 0; ct < 4; ++ct) {
            bf16x8 bcur[4];
#pragma unroll
            for (int ks = 0; ks < 4; ++ks)
                bcur[ks] = *(const bf16x8*)(buf + dsbase[ks] + ct * 2048);

            const int ctile = col0 + ch * CHUNK_COLS + ct * 16;
            __builtin_amdgcn_s_setprio(1);
#pragma unroll
            for (int rs = 0; rs < 4; ++rs) {
                f32x4 s = __builtin_amdgcn_mfma_f32_16x16x32_bf16(
                    afrag[rs][0], bcur[0], zinit, 0, 0, 0);
#pragma unroll
                for (int ks = 1; ks < 4; ++ks)
                    s = __builtin_amdgcn_mfma_f32_16x16x32_bf16(
                        afrag[rs][ks], bcur[ks], s, 0, 0, 0);
                if (ctile == rows0 + rs * 16) {    // diagonal tile: -1e6
#pragma unroll
                    for (int r = 0; r < 4; ++r)
                        if (quad * 4 + r == lane16) s[r] -= 1.0e6f;
                }
#pragma unroll
                for (int r = 0; r < 4; ++r)
                    runmax[rs][r] = fmaxf(runmax[rs][r], s[r]);
            }
            __builtin_amdgcn_s_setprio(0);
        }
    }

    // reduce max across the 16 lanes (cols) of each quad-group
#pragma unroll
    for (int rs = 0; rs < 4; ++rs)
#pragma unroll
        for (int r = 0; r < 4; ++r) {
            float m = runmax[rs][r];
            m = fmaxf(m, __shfl_xor(m, 1));
            m = fmaxf(m, __shfl_xor(m, 2));
            m = fmaxf(m, __shfl_xor(m, 4));
            m = fmaxf(m, __shfl_xor(m, 8));
            runmax[rs][r] = m;
        }

    // partial row-max for this col-group -> global [NCG][BATCH]
    if (lane16 == 0) {
#pragma unroll
        for (int rs = 0; rs < 4; ++rs)
#pragma unroll
            for (int r = 0; r < 4; ++r)
                partials[(size_t)cg * BATCH + rows0 + rs * 16 + quad * 4 + r] =
                    runmax[rs][r];
    }
}

// ---------------------------------------------------------------------------
// Kernel C: combine col-group partials, softplus, per-block sums (no atomics).
// ---------------------------------------------------------------------------
__global__ __launch_bounds__(256) void reduce_kernel(
    const float* __restrict__ partials, const float* __restrict__ pos,
    float* __restrict__ red_part)
{
    const int t = threadIdx.x;
    const int r = blockIdx.x * 256 + t;
    float fm = partials[r];
#pragma unroll
    for (int cgi = 1; cgi < NCG; ++cgi)
        fm = fmaxf(fm, partials[(size_t)cgi * BATCH + r]);
    float c = softplus_f(fm - pos[r]);
    c += __shfl_xor(c, 1);  c += __shfl_xor(c, 2);
    c += __shfl_xor(c, 4);  c += __shfl_xor(c, 8);
    c += __shfl_xor(c, 16); c += __shfl_xor(c, 32);

    __shared__ float red[4];
    if ((t & 63) == 0) red[t >> 6] = c;
    __syncthreads();
    if (t == 0)
        red_part[blockIdx.x] = red[0] + red[1] + red[2] + red[3];
}

// ---------------------------------------------------------------------------
// Kernel D: final sum of loss1_part[2048] + red_part[64] -> scalar loss.
// ---------------------------------------------------------------------------
__global__ __launch_bounds__(256) void finalize_kernel(
    const float* __restrict__ loss1_part, const float* __restrict__ red_part,
    float* __restrict__ out)
{
    const int t = threadIdx.x;
    float s = 0.0f;
#pragma unroll
    for (int i = 0; i < NPREP / 256; ++i)
        s += loss1_part[i * 256 + t];
    if (t < NRED) s += red_part[t];
    s += __shfl_xor(s, 1);  s += __shfl_xor(s, 2);
    s += __shfl_xor(s, 4);  s += __shfl_xor(s, 8);
    s += __shfl_xor(s, 16); s += __shfl_xor(s, 32);

    __shared__ float red[4];
    if ((t & 63) == 0) red[t >> 6] = s;
    __syncthreads();
    if (t == 0)
        out[0] = (red[0] + red[1] + red[2] + red[3]) * (1.0f / (2.0f * BATCH));
}

extern "C" void kernel_launch(void* const* d_in, const int* in_sizes, int n_in,
                              void* d_out, int out_size, void* d_ws, size_t ws_size,
                              hipStream_t stream)
{
    const float* q  = (const float*)d_in[0];
    const float* d  = (const float*)d_in[1];
    const float* nd = (const float*)d_in[2];
    float* out = (float*)d_out;

    char* ws = (char*)d_ws;
    float*  pos        = (float*)ws;                                 // 64 KB
    ushort* qb         = (ushort*)(ws + 65536);                      // 4 MB
    ushort* db         = (ushort*)(ws + 65536 + 4194304);            // 4 MB
    float*  partials   = (float*)(ws + 65536 + 2 * 4194304);         // 1 MB
    float*  loss1_part = (float*)(ws + 65536 + 2 * 4194304 + 1048576);     // 8 KB
    float*  red_part   = (float*)(ws + 65536 + 2 * 4194304 + 1048576 + 8192); // 256 B

    prep_kernel<<<NPREP, 256, 0, stream>>>(q, d, nd, qb, db, pos, loss1_part);
    inbatch_kernel<<<NRG * NCG, 256, 0, stream>>>(qb, db, partials);
    reduce_kernel<<<NRED, 256, 0, stream>>>(partials, pos, red_part);
    finalize_kernel<<<1, 256, 0, stream>>>(loss1_part, red_part, out);
}

// Round 4
// 347.183 us; speedup vs baseline: 1.2954x; 1.1656x over previous
//
#include <hip/hip_runtime.h>
#include <hip/hip_bf16.h>

// BiPairwiseNegativeCELoss on MI355X.
// Inputs: q, d, nd : [16384, 128] fp32. Output: scalar fp32 loss.
// loss = 0.5 * ( mean(softplus(q.nd_row - q.d_row))
//              + mean(softplus(max_c(q_b . d_c, diag -1e6) - q_b.d_b)) )
//
// R12: make the 4-waves/SIMD tier actually FIT. Occupancy tiers are 64/128/256
// combined regs (m69); 3 waves/SIMD does not exist. R10/R11 asked for the
// 128 tier with ~140+ combined demand -> afrag (64 regs) spilled to scratch
// (FETCH 0.9-1.2 GB, ~900KB/block = 64KB afrag x 16 chunk reloads).
// afrag=64 is irreducible (64 rows x 128 K x 2B / 64 lanes) and 64 rows/wave
// is required (32-row waves make the fixed 16KB/wave/chunk B ds_read exceed
// the halved MFMA time -> LDS-bound). So shave ADDRESSING fat instead:
//   - staging addresses as uniform base + ONE 32-bit lane_elem VGPR (saddr
//     form), replacing 4 precomputed 64-bit gsrc pointers (8 VGPRs + per-chunk
//     vector adds).
//   - diagonal test hoisted to uniform (diagblk && ch==chd && ct==rs); no
//     per-tile ctile register.
// New demand ~115 combined < 128. Decisive counter: FETCH_SIZE ~18.5 MB (fit)
// vs ~1 GB (spill, revert).
// Also: merge reduce+finalize (last-block pattern, deterministic, same
// summation order) -- the total-vs-inbatch gap is a constant ~58-70us of
// fixed overhead; one fewer launch shaves ~10us of it.
// Same shapes/layouts/numerics (absmax must stay 0.0).

#define BATCH 16384
#define DDIM  128
#define NWAVES 4                 // 256 threads
#define ROWS_PER_BLOCK 256       // 4 waves x 64 rows
#define COLS_PER_BLOCK 1024      // 16 col-groups
#define CHUNK_COLS 64            // 16 KB bf16 per chunk buffer
#define NCHUNKS (COLS_PER_BLOCK / CHUNK_COLS)   // 16
#define CHUNK_USHORTS (CHUNK_COLS * DDIM)       // 8192
#define NCG (BATCH / COLS_PER_BLOCK)            // 16
#define NRG (BATCH / ROWS_PER_BLOCK)            // 64
#define NPREP 2048                               // prep blocks (8 rows each)
#define NRED  64                                 // reduce blocks

typedef __attribute__((ext_vector_type(8))) short bf16x8;   // 8 bf16 = 4 VGPRs
typedef __attribute__((ext_vector_type(4))) float f32x4;

__device__ __forceinline__ float softplus_f(float x) {
    return (x > 0.0f) ? x + log1pf(expf(-x)) : log1pf(expf(x));
}

__device__ __forceinline__ ushort f2bf_rne(float x) {
    unsigned u = __float_as_uint(x);
    unsigned r = (u + 0x7FFFu + ((u >> 16) & 1u)) >> 16;
    return (ushort)r;
}

#define WAITVM(n) do { \
        __builtin_amdgcn_s_waitcnt((n) | (7 << 4) | (15 << 8)); \
        asm volatile("" ::: "memory"); \
    } while (0)

#define BARRIER() do { \
        __builtin_amdgcn_s_barrier(); \
        asm volatile("" ::: "memory"); \
    } while (0)

// ---------------------------------------------------------------------------
// Kernel A: pairwise dots (fp32 exact), loss1 block partials, bf16 casts.
// 2048 blocks x 256 threads. Block owns 8 rows; 32 threads per row.
// Also zeroes the reduce ticket for this iteration (visible at next dispatch).
// ---------------------------------------------------------------------------
__global__ __launch_bounds__(256) void prep_kernel(
    const float* __restrict__ q, const float* __restrict__ d,
    const float* __restrict__ nd,
    ushort* __restrict__ qb, ushort* __restrict__ db,
    float* __restrict__ pos, float* __restrict__ loss1_part,
    unsigned* __restrict__ ticket)
{
    const int t   = threadIdx.x;
    const int sub = t >> 5;                      // row 0..7 within block
    const int ln  = t & 31;                      // 32 threads per row
    const int row = blockIdx.x * 8 + sub;
    const size_t idx = (size_t)row * DDIM + ln * 4;

    if (blockIdx.x == 0 && t == 0) ticket[0] = 0u;

    float4 a = *(const float4*)(q  + idx);
    float4 b = *(const float4*)(d  + idx);
    float4 c = *(const float4*)(nd + idx);

    ushort4 o;
    o.x = f2bf_rne(a.x); o.y = f2bf_rne(a.y);
    o.z = f2bf_rne(a.z); o.w = f2bf_rne(a.w);
    *(ushort4*)(qb + idx) = o;
    ushort4 p;
    p.x = f2bf_rne(b.x); p.y = f2bf_rne(b.y);
    p.z = f2bf_rne(b.z); p.w = f2bf_rne(b.w);
    *(ushort4*)(db + idx) = p;

    float ps = a.x * b.x + a.y * b.y + a.z * b.z + a.w * b.w;
    float ns = a.x * c.x + a.y * c.y + a.z * c.z + a.w * c.w;
    ps += __shfl_xor(ps, 1); ps += __shfl_xor(ps, 2);
    ps += __shfl_xor(ps, 4); ps += __shfl_xor(ps, 8);
    ps += __shfl_xor(ps, 16);
    ns += __shfl_xor(ns, 1); ns += __shfl_xor(ns, 2);
    ns += __shfl_xor(ns, 4); ns += __shfl_xor(ns, 8);
    ns += __shfl_xor(ns, 16);

    float contrib = 0.0f;
    if (ln == 0) {
        pos[row] = ps;                     // == scores[b][b], exact fp32
        contrib = softplus_f(ns - ps);
    }
    contrib += __shfl_xor(contrib, 32);    // combine the wave's two rows

    __shared__ float red[4];
    if ((t & 63) == 0) red[t >> 6] = contrib;
    __syncthreads();
    if (t == 0)
        loss1_part[blockIdx.x] = red[0] + red[1] + red[2] + red[3];
}

// ---------------------------------------------------------------------------
// Kernel B: fused GEMM + row-max. 1024 blocks x 256 threads, target 4
// blocks/CU. Block (rg = bx&63, cg = bx>>6): rows [rg*256,+256), cols
// [cg*1024,+1024). Wave w owns 64 rows (A in registers, whole K). B staged
// cooperatively: 64-col chunks, 2x16KB LDS double buffer, XOR-swizzled 16B
// k-segments. Addressing kept scalar/uniform wherever possible so combined
// reg demand stays under the 128 tier.
// ---------------------------------------------------------------------------
__global__ __launch_bounds__(256, 4) void inbatch_kernel(
    const ushort* __restrict__ qb, const ushort* __restrict__ db,
    float* __restrict__ partials)
{
    __shared__ ushort stg[2][CHUNK_USHORTS];   // 2 x 16 KB

    const int t      = threadIdx.x;
    const int w      = t >> 6;
    const int lane16 = t & 15;
    const int quad   = (t >> 4) & 3;
    const int rg     = blockIdx.x & 63;
    const int cg     = blockIdx.x >> 6;
    const int rows0  = rg * ROWS_PER_BLOCK + w * 64;   // this wave's 64 rows
    const int col0   = cg * COLS_PER_BLOCK;

    // A fragments: lane l holds Q[rows0 + rs*16 + (l&15)][ks*32 + quad*8 + j]
    bf16x8 afrag[4][4];
#pragma unroll
    for (int rs = 0; rs < 4; ++rs)
#pragma unroll
        for (int ks = 0; ks < 4; ++ks)
            afrag[rs][ks] = *(const bf16x8*)(
                qb + (size_t)(rows0 + rs * 16 + lane16) * DDIM + ks * 32 + quad * 8);

    // staging: thread t handles 16B segment (i*16 + (t>>4)) cols, XOR-swizzled
    // k-segment. Per-lane part is ONE 32-bit offset; chunk/i parts uniform.
    const int lane_elem = (t >> 4) * DDIM + (((t & 15) ^ ((t >> 4) & 15)) * 8);
    const ushort* dbase = db + (size_t)col0 * DDIM;    // uniform base

    // stage chunk cc of B into LDS buffer bb (dest: wave-uniform + lane*16B)
#define STAGE(cc, bb) do { \
        const ushort* _s = dbase + (size_t)(cc) * CHUNK_USHORTS; \
        _Pragma("unroll") \
        for (int _i = 0; _i < 4; ++_i) \
            __builtin_amdgcn_global_load_lds( \
                (const __attribute__((address_space(1))) void*)(_s + _i * 2048 + lane_elem), \
                (__attribute__((address_space(3))) void*)(&stg[bb][0] + (_i * 256 + w * 64) * 8), \
                16, 0, 0); \
    } while (0)

    // ds_read base (ushort offsets); per-(ct,buf) selected by pointer + imm
    int dsbase[4];
#pragma unroll
    for (int ks = 0; ks < 4; ++ks)
        dsbase[ks] = lane16 * DDIM + (((ks * 4 + quad) ^ lane16) * 8);

    // diagonal handling: only the (unique) chunk chd of the wave's own rows,
    // tile ct == rs there. Uniform predicate, no per-tile ctile register.
    const bool diagblk = ((rows0 >> 10) == cg);
    const int  chd     = (rows0 - col0) >> 6;          // valid iff diagblk

    const f32x4 zinit = {0.0f, 0.0f, 0.0f, 0.0f};

    float runmax[4][4];
#pragma unroll
    for (int rs = 0; rs < 4; ++rs)
#pragma unroll
        for (int r = 0; r < 4; ++r) runmax[rs][r] = -3.0e38f;

    STAGE(0, 0);                             // prologue

    for (int ch = 0; ch < NCHUNKS; ++ch) {
        // outstanding here: exactly chunk ch's 4 loads (issued last iteration,
        // had the whole previous compute phase to land)
        WAITVM(0);
        BARRIER();                           // chunk ch visible; buf ch^1 free
        if (ch + 1 < NCHUNKS)
            STAGE(ch + 1, (ch + 1) & 1);     // lands under this compute phase

        const ushort* buf = &stg[ch & 1][0];

#pragma unroll
        for (int ct = 0; ct < 4; ++ct) {
            bf16x8 bcur[4];
#pragma unroll
            for (int ks = 0; ks < 4; ++ks)
                bcur[ks] = *(const bf16x8*)(buf + dsbase[ks] + ct * 2048);

            __builtin_amdgcn_s_setprio(1);
#pragma unroll
            for (int rs = 0; rs < 4; ++rs) {
                f32x4 s = __builtin_amdgcn_mfma_f32_16x16x32_bf16(
                    afrag[rs][0], bcur[0], zinit, 0, 0, 0);
#pragma unroll
                for (int ks = 1; ks < 4; ++ks)
                    s = __builtin_amdgcn_mfma_f32_16x16x32_bf16(
                        afrag[rs][ks], bcur[ks], s, 0, 0, 0);
                if (diagblk && ch == chd && ct == rs) {   // diagonal: -1e6
#pragma unroll
                    for (int r = 0; r < 4; ++r)
                        if (quad * 4 + r == lane16) s[r] -= 1.0e6f;
                }
#pragma unroll
                for (int r = 0; r < 4; ++r)
                    runmax[rs][r] = fmaxf(runmax[rs][r], s[r]);
            }
            __builtin_amdgcn_s_setprio(0);
        }
    }
#undef STAGE

    // reduce max across the 16 lanes (cols) of each quad-group
#pragma unroll
    for (int rs = 0; rs < 4; ++rs)
#pragma unroll
        for (int r = 0; r < 4; ++r) {
            float m = runmax[rs][r];
            m = fmaxf(m, __shfl_xor(m, 1));
            m = fmaxf(m, __shfl_xor(m, 2));
            m = fmaxf(m, __shfl_xor(m, 4));
            m = fmaxf(m, __shfl_xor(m, 8));
            runmax[rs][r] = m;
        }

    // partial row-max for this col-group -> global [NCG][BATCH]
    if (lane16 == 0) {
#pragma unroll
        for (int rs = 0; rs < 4; ++rs)
#pragma unroll
            for (int r = 0; r < 4; ++r)
                partials[(size_t)cg * BATCH + rows0 + rs * 16 + quad * 4 + r] =
                    runmax[rs][r];
    }
}

// ---------------------------------------------------------------------------
// Kernel C: combine col-group partials, softplus, per-block sums; the LAST
// block (device-scope atomic ticket) also folds in loss1_part and writes the
// final scalar. Summation order identical to the old finalize_kernel.
// ---------------------------------------------------------------------------
__global__ __launch_bounds__(256) void reduce_fin_kernel(
    const float* __restrict__ partials, const float* __restrict__ pos,
    const float* __restrict__ loss1_part,
    float* __restrict__ red_part, unsigned* __restrict__ ticket,
    float* __restrict__ out)
{
    const int t = threadIdx.x;
    const int r = blockIdx.x * 256 + t;
    float fm = partials[r];
#pragma unroll
    for (int cgi = 1; cgi < NCG; ++cgi)
        fm = fmaxf(fm, partials[(size_t)cgi * BATCH + r]);
    float c = softplus_f(fm - pos[r]);
    c += __shfl_xor(c, 1);  c += __shfl_xor(c, 2);
    c += __shfl_xor(c, 4);  c += __shfl_xor(c, 8);
    c += __shfl_xor(c, 16); c += __shfl_xor(c, 32);

    __shared__ float red[4];
    __shared__ int lastflag;
    if ((t & 63) == 0) red[t >> 6] = c;
    __syncthreads();
    if (t == 0) {
        float bs = red[0] + red[1] + red[2] + red[3];
        atomicExch(&red_part[blockIdx.x], bs);   // device-scope visible
        __threadfence();
        unsigned old = atomicAdd(ticket, 1u);
        lastflag = (old == NRED - 1) ? 1 : 0;
    }
    __syncthreads();
    if (lastflag) {
        float s = 0.0f;
#pragma unroll
        for (int i = 0; i < NPREP / 256; ++i)
            s += loss1_part[i * 256 + t];
        if (t < NRED) s += atomicAdd(&red_part[t], 0.0f);  // coherent read
        s += __shfl_xor(s, 1);  s += __shfl_xor(s, 2);
        s += __shfl_xor(s, 4);  s += __shfl_xor(s, 8);
        s += __shfl_xor(s, 16); s += __shfl_xor(s, 32);
        if ((t & 63) == 0) red[t >> 6] = s;
        __syncthreads();
        if (t == 0)
            out[0] = (red[0] + red[1] + red[2] + red[3]) * (1.0f / (2.0f * BATCH));
    }
}

extern "C" void kernel_launch(void* const* d_in, const int* in_sizes, int n_in,
                              void* d_out, int out_size, void* d_ws, size_t ws_size,
                              hipStream_t stream)
{
    const float* q  = (const float*)d_in[0];
    const float* d  = (const float*)d_in[1];
    const float* nd = (const float*)d_in[2];
    float* out = (float*)d_out;

    char* ws = (char*)d_ws;
    float*    pos        = (float*)ws;                                 // 64 KB
    ushort*   qb         = (ushort*)(ws + 65536);                      // 4 MB
    ushort*   db         = (ushort*)(ws + 65536 + 4194304);            // 4 MB
    float*    partials   = (float*)(ws + 65536 + 2 * 4194304);         // 1 MB
    float*    loss1_part = (float*)(ws + 65536 + 2 * 4194304 + 1048576);     // 8 KB
    float*    red_part   = (float*)(ws + 65536 + 2 * 4194304 + 1048576 + 8192); // 256 B
    unsigned* ticket     = (unsigned*)(ws + 65536 + 2 * 4194304 + 1048576 + 8192 + 256);

    prep_kernel<<<NPREP, 256, 0, stream>>>(q, d, nd, qb, db, pos, loss1_part, ticket);
    inbatch_kernel<<<NRG * NCG, 256, 0, stream>>>(qb, db, partials);
    reduce_fin_kernel<<<NRED, 256, 0, stream>>>(partials, pos, loss1_part,
                                                red_part, ticket, out);
}